// Round 3
// baseline (1048.702 us; speedup 1.0000x reference)
//
#include <hip/hip_runtime.h>
#include <hip/hip_bf16.h>
#include <math.h>

#define T_TOK 1024
#define H_DIM 2048
#define I_DIM 768
#define E_NUM 32
#define K_TOP 8

#define BK  32
#define LDP 40   // padded LDS row (bf16): 80B stride, keeps 16B alignment

typedef __bf16 bf16x8 __attribute__((ext_vector_type(8)));
typedef float  f32x4  __attribute__((ext_vector_type(4)));

__device__ __forceinline__ bf16x8 cvt2_bf16(const f32x4 a, const f32x4 b) {
    bf16x8 r;
    r[0] = (__bf16)a[0]; r[1] = (__bf16)a[1]; r[2] = (__bf16)a[2]; r[3] = (__bf16)a[3];
    r[4] = (__bf16)b[0]; r[5] = (__bf16)b[1]; r[6] = (__bf16)b[2]; r[7] = (__bf16)b[3];
    return r;
}

// ---------------- Router: logits -> top-8 -> normalized weights -------------
__global__ __launch_bounds__(256) void router_kernel(
    const float* __restrict__ x, const float* __restrict__ gw,
    float* __restrict__ wdense, unsigned int* __restrict__ masks)
{
    const int t = blockIdx.x;
    const int tid = threadIdx.x;
    __shared__ float part[256];
    __shared__ float logits[E_NUM];
    const int e = tid & 31;
    const int chunk = tid >> 5;
    const float* xr = x + (size_t)t * H_DIM;
    const float* gr = gw + (size_t)e * H_DIM;
    const int base = chunk * (H_DIM / 8);
    float s = 0.f;
    for (int h = 0; h < H_DIM / 8; h += 4) {
        const f32x4 xv = *reinterpret_cast<const f32x4*>(xr + base + h);
        const f32x4 gv = *reinterpret_cast<const f32x4*>(gr + base + h);
        s += xv[0]*gv[0] + xv[1]*gv[1] + xv[2]*gv[2] + xv[3]*gv[3];
    }
    part[tid] = s;
    __syncthreads();
    if (tid < E_NUM) {
        float tot = 0.f;
        for (int c = 0; c < 8; ++c) tot += part[c * 32 + tid];
        logits[tid] = tot;
    }
    __syncthreads();
    if (tid == 0) {
        float l[E_NUM];
        for (int i = 0; i < E_NUM; ++i) {
            l[i] = logits[i];
            wdense[(size_t)t * E_NUM + i] = 0.f;
        }
        unsigned mask = 0;
        int   idx[K_TOP];
        float lv[K_TOP];
        for (int k = 0; k < K_TOP; ++k) {
            float best = -1e30f; int bi = 0;
            for (int i = 0; i < E_NUM; ++i)
                if (!((mask >> i) & 1u) && l[i] > best) { best = l[i]; bi = i; }
            mask |= (1u << bi); idx[k] = bi; lv[k] = best;
        }
        const float m = lv[0];
        float den = 0.f;
        for (int k = 0; k < K_TOP; ++k) den += expf(lv[k] - m);
        for (int k = 0; k < K_TOP; ++k)
            wdense[(size_t)t * E_NUM + idx[k]] = expf(lv[k] - m) / den;
        masks[t] = mask;
    }
}

// ---------------- Build compacted per-expert token lists --------------------
__global__ __launch_bounds__(256) void count_kernel(
    const unsigned int* __restrict__ masks, int* __restrict__ cnt)
{
    const int e = blockIdx.x;
    const int tid = threadIdx.x;
    int c = 0;
    for (int t = tid; t < T_TOK; t += 256) c += (masks[t] >> e) & 1u;
    __shared__ int red[256];
    red[tid] = c; __syncthreads();
    for (int s = 128; s > 0; s >>= 1) {
        if (tid < s) red[tid] += red[tid + s];
        __syncthreads();
    }
    if (tid == 0) cnt[e] = red[0];
}

__global__ void scan_kernel(const int* __restrict__ cnt, int* __restrict__ off)
{
    if (threadIdx.x == 0 && blockIdx.x == 0) {
        int r = 0;
        for (int e = 0; e < E_NUM; ++e) { off[e] = r; r += cnt[e]; }
    }
}

__global__ __launch_bounds__(256) void fill_kernel(
    const unsigned int* __restrict__ masks, const float* __restrict__ wdense,
    const int* __restrict__ off, int* __restrict__ tok, float* __restrict__ wgt)
{
    const int e = blockIdx.x;
    const int tid = threadIdx.x;
    const int PER = T_TOK / 256;
    int sel[PER]; int c = 0;
    for (int i = 0; i < PER; ++i) {
        const int t = tid * PER + i;
        sel[i] = (masks[t] >> e) & 1u;
        c += sel[i];
    }
    __shared__ int s[256];
    s[tid] = c; __syncthreads();
    if (tid == 0) {
        int r = 0;
        for (int j = 0; j < 256; ++j) { int v = s[j]; s[j] = r; r += v; }
    }
    __syncthreads();
    int pos = off[e] + s[tid];
    for (int i = 0; i < PER; ++i) {
        if (sel[i]) {
            const int t = tid * PER + i;
            tok[pos] = t;
            wgt[pos] = wdense[(size_t)t * E_NUM + e];
            pos++;
        }
    }
}

// ---------------- GEMM1: act = silu(x @ w1^T) * (x @ w3^T) ------------------
// grid (E*4, I/64), block 512 (8 waves). Block: 256 tokens x 64 I-cols.
// B-tile rows (128): [0:32)=gate lo, [32:64)=up lo, [64:96)=gate hi, [96:128)=up hi.
// Wave (4Mx2N): 64 tokens x 64 B-rows -> acc[4][4]; n=0,1 gate, n=2,3 up.
__global__ __launch_bounds__(512) void gemm1_kernel(
    const float* __restrict__ x, const float* __restrict__ w13,
    const int* __restrict__ tok, const int* __restrict__ cnt,
    const int* __restrict__ off, unsigned short* __restrict__ act)
{
    const int e  = blockIdx.x >> 2;
    const int zt = blockIdx.x & 3;
    const int c = cnt[e];
    const int m0 = zt * 256;
    if (m0 >= c) return;
    const int o  = off[e];
    const int n0 = blockIdx.y * 64;
    const int tid  = threadIdx.x;
    const int wid  = tid >> 6;
    const int lane = tid & 63;
    const int wm = (wid >> 1) * 64;     // 0,64,128,192
    const int wn = (wid & 1) * 64;      // 0,64 (B-row offset)
    const int lrow = lane & 15;
    const int kgrp = (lane >> 4) * 8;

    __shared__ __align__(16) __bf16 As[2][256][LDP];
    __shared__ __align__(16) __bf16 Bs[2][128][LDP];

    // A staging: thread -> row tid>>1, 16 floats at col (tid&1)*16
    const int srowA = tid >> 1;
    const int scolA = (tid & 1) * 16;
    int rA = m0 + srowA; rA = rA < c ? rA : c - 1;
    const float* xp = x + (size_t)tok[o + rA] * H_DIM + scolA;
    // B staging: thread -> row tid>>2, 8 floats at col (tid&3)*8
    const int srowB = tid >> 2;
    const int scolB = (tid & 3) * 8;
    const int grp = srowB >> 5;
    const int wrow = (grp & 1) * I_DIM + n0 + (grp >> 1) * 32 + (srowB & 31);
    const float* wp = w13 + (size_t)e * (2 * I_DIM) * H_DIM + (size_t)wrow * H_DIM + scolB;

    f32x4 ra[4], rb[2];
    f32x4 acc[4][4] = {};

#pragma unroll
    for (int i = 0; i < 4; ++i) ra[i] = *(const f32x4*)(xp + i * 4);
    rb[0] = *(const f32x4*)(wp);
    rb[1] = *(const f32x4*)(wp + 4);
    *(bf16x8*)&As[0][srowA][scolA]     = cvt2_bf16(ra[0], ra[1]);
    *(bf16x8*)&As[0][srowA][scolA + 8] = cvt2_bf16(ra[2], ra[3]);
    *(bf16x8*)&Bs[0][srowB][scolB]     = cvt2_bf16(rb[0], rb[1]);
    __syncthreads();

    const int NS = H_DIM / BK;   // 64
    for (int s = 0; s < NS; ++s) {
        const int buf = s & 1;
        if (s + 1 < NS) {
            const int k = (s + 1) * BK;
#pragma unroll
            for (int i = 0; i < 4; ++i) ra[i] = *(const f32x4*)(xp + k + i * 4);
            rb[0] = *(const f32x4*)(wp + k);
            rb[1] = *(const f32x4*)(wp + k + 4);
        }
        bf16x8 af[4], bfr[4];
#pragma unroll
        for (int m = 0; m < 4; ++m)
            af[m] = *(const bf16x8*)&As[buf][wm + m * 16 + lrow][kgrp];
#pragma unroll
        for (int n = 0; n < 4; ++n)
            bfr[n] = *(const bf16x8*)&Bs[buf][wn + n * 16 + lrow][kgrp];
#pragma unroll
        for (int m = 0; m < 4; ++m)
#pragma unroll
            for (int n = 0; n < 4; ++n)
                acc[m][n] = __builtin_amdgcn_mfma_f32_16x16x32_bf16(af[m], bfr[n], acc[m][n], 0, 0, 0);
        if (s + 1 < NS) {
            *(bf16x8*)&As[buf ^ 1][srowA][scolA]     = cvt2_bf16(ra[0], ra[1]);
            *(bf16x8*)&As[buf ^ 1][srowA][scolA + 8] = cvt2_bf16(ra[2], ra[3]);
            *(bf16x8*)&Bs[buf ^ 1][srowB][scolB]     = cvt2_bf16(rb[0], rb[1]);
        }
        __syncthreads();
    }

    // epilogue: B rows [wn + n*16): n=0,1 gate; n=2,3 up; icol = n0 + wn/2 + n*16 + lrow
#pragma unroll
    for (int m = 0; m < 4; ++m)
#pragma unroll
        for (int n = 0; n < 2; ++n)
#pragma unroll
            for (int i = 0; i < 4; ++i) {
                const int row = m0 + wm + m * 16 + (lane >> 4) * 4 + i;
                if (row < c) {
                    const int icol = n0 + (wn >> 1) + n * 16 + lrow;
                    const float g = acc[m][n][i];
                    const float u = acc[m][n + 2][i];
                    const float a = (g / (1.f + expf(-g))) * u;
                    act[(size_t)(o + row) * I_DIM + icol] =
                        __builtin_bit_cast(unsigned short, (__bf16)a);
                }
            }
}

// ---------------- GEMM2: out[t] += wgt * (act @ w2^T) -----------------------
// grid (E*4, H/256), block 512 (8 waves). Block: 256 tokens x 256 H-cols.
// Wave (4Mx2N): 64 tokens x 128 H-cols -> acc[4][8].
__global__ __launch_bounds__(512) void gemm2_kernel(
    const unsigned short* __restrict__ act, const float* __restrict__ w2,
    const int* __restrict__ tok, const float* __restrict__ wgt,
    const int* __restrict__ cnt, const int* __restrict__ off,
    float* __restrict__ out)
{
    const int e  = blockIdx.x >> 2;
    const int zt = blockIdx.x & 3;
    const int c = cnt[e];
    const int m0 = zt * 256;
    if (m0 >= c) return;
    const int o  = off[e];
    const int n0 = blockIdx.y * 256;
    const int tid  = threadIdx.x;
    const int wid  = tid >> 6;
    const int lane = tid & 63;
    const int wm = (wid >> 1) * 64;     // 0,64,128,192
    const int wn = (wid & 1) * 128;     // 0,128
    const int lrow = lane & 15;
    const int kgrp = (lane >> 4) * 8;

    __shared__ __align__(16) __bf16 As[2][256][LDP];
    __shared__ __align__(16) __bf16 Bs[2][256][LDP];

    const int srow = tid >> 1;
    const int scol = (tid & 1) * 16;
    int rA = m0 + srow; rA = rA < c ? rA : c - 1;
    const unsigned short* ap = act + (size_t)(o + rA) * I_DIM + scol;
    const float* wp = w2 + (size_t)e * H_DIM * I_DIM + (size_t)(n0 + srow) * I_DIM + scol;

    bf16x8 raa[2];
    f32x4  rbb[4];
    f32x4  acc[4][8] = {};

    raa[0] = *(const bf16x8*)(ap);
    raa[1] = *(const bf16x8*)(ap + 8);
#pragma unroll
    for (int i = 0; i < 4; ++i) rbb[i] = *(const f32x4*)(wp + i * 4);
    *(bf16x8*)&As[0][srow][scol]     = raa[0];
    *(bf16x8*)&As[0][srow][scol + 8] = raa[1];
    *(bf16x8*)&Bs[0][srow][scol]     = cvt2_bf16(rbb[0], rbb[1]);
    *(bf16x8*)&Bs[0][srow][scol + 8] = cvt2_bf16(rbb[2], rbb[3]);
    __syncthreads();

    const int NS = I_DIM / BK;   // 24
    for (int s = 0; s < NS; ++s) {
        const int buf = s & 1;
        if (s + 1 < NS) {
            const int k = (s + 1) * BK;
            raa[0] = *(const bf16x8*)(ap + k);
            raa[1] = *(const bf16x8*)(ap + k + 8);
#pragma unroll
            for (int i = 0; i < 4; ++i) rbb[i] = *(const f32x4*)(wp + k + i * 4);
        }
        bf16x8 af[4], bfr[8];
#pragma unroll
        for (int m = 0; m < 4; ++m)
            af[m] = *(const bf16x8*)&As[buf][wm + m * 16 + lrow][kgrp];
#pragma unroll
        for (int n = 0; n < 8; ++n)
            bfr[n] = *(const bf16x8*)&Bs[buf][wn + n * 16 + lrow][kgrp];
#pragma unroll
        for (int m = 0; m < 4; ++m)
#pragma unroll
            for (int n = 0; n < 8; ++n)
                acc[m][n] = __builtin_amdgcn_mfma_f32_16x16x32_bf16(af[m], bfr[n], acc[m][n], 0, 0, 0);
        if (s + 1 < NS) {
            *(bf16x8*)&As[buf ^ 1][srow][scol]     = raa[0];
            *(bf16x8*)&As[buf ^ 1][srow][scol + 8] = raa[1];
            *(bf16x8*)&Bs[buf ^ 1][srow][scol]     = cvt2_bf16(rbb[0], rbb[1]);
            *(bf16x8*)&Bs[buf ^ 1][srow][scol + 8] = cvt2_bf16(rbb[2], rbb[3]);
        }
        __syncthreads();
    }

#pragma unroll
    for (int m = 0; m < 4; ++m)
#pragma unroll
        for (int n = 0; n < 8; ++n)
#pragma unroll
            for (int i = 0; i < 4; ++i) {
                const int row = m0 + wm + m * 16 + (lane >> 4) * 4 + i;
                if (row < c) {
                    const int t = tok[o + row];
                    const float w = wgt[o + row];
                    const int hcol = n0 + wn + n * 16 + lrow;
                    atomicAdd(&out[(size_t)t * H_DIM + hcol], w * acc[m][n][i]);
                }
            }
}

// ---------------- Launch ----------------------------------------------------
extern "C" void kernel_launch(void* const* d_in, const int* in_sizes, int n_in,
                              void* d_out, int out_size, void* d_ws, size_t ws_size,
                              hipStream_t stream)
{
    const float* x   = (const float*)d_in[0];
    const float* gw  = (const float*)d_in[1];
    const float* w13 = (const float*)d_in[2];
    const float* w2  = (const float*)d_in[3];
    float* out = (float*)d_out;

    char* ws = (char*)d_ws;
    float*          wdense = (float*)(ws + 0x00000);
    unsigned int*   masks  = (unsigned int*)(ws + 0x20000);
    int*            cnt    = (int*)(ws + 0x21000);
    int*            off    = (int*)(ws + 0x22000);
    int*            tok    = (int*)(ws + 0x23000);
    float*          wgt    = (float*)(ws + 0x2B000);
    unsigned short* act    = (unsigned short*)(ws + 0x33000);

    hipMemsetAsync(d_out, 0, (size_t)out_size * sizeof(float), stream);

    router_kernel<<<T_TOK, 256, 0, stream>>>(x, gw, wdense, masks);
    count_kernel<<<E_NUM, 256, 0, stream>>>(masks, cnt);
    scan_kernel<<<1, 64, 0, stream>>>(cnt, off);
    fill_kernel<<<E_NUM, 256, 0, stream>>>(masks, wdense, off, tok, wgt);
    gemm1_kernel<<<dim3(E_NUM * 4, I_DIM / 64), 512, 0, stream>>>(
        x, w13, tok, cnt, off, act);
    gemm2_kernel<<<dim3(E_NUM * 4, H_DIM / 256), 512, 0, stream>>>(
        act, w2, tok, wgt, cnt, off, out);
}

// Round 4
// 1047.232 us; speedup vs baseline: 1.0014x; 1.0014x over previous
//
#include <hip/hip_runtime.h>
#include <hip/hip_bf16.h>
#include <math.h>

#define T_TOK 1024
#define H_DIM 2048
#define I_DIM 768
#define E_NUM 32
#define K_TOP 8
#define BK 32

typedef __bf16 bf16x8 __attribute__((ext_vector_type(8)));
typedef float  f32x4  __attribute__((ext_vector_type(4)));

__device__ __forceinline__ bf16x8 cvt2_bf16(const f32x4 a, const f32x4 b) {
    bf16x8 r;
    r[0] = (__bf16)a[0]; r[1] = (__bf16)a[1]; r[2] = (__bf16)a[2]; r[3] = (__bf16)a[3];
    r[4] = (__bf16)b[0]; r[5] = (__bf16)b[1]; r[6] = (__bf16)b[2]; r[7] = (__bf16)b[3];
    return r;
}

// LDS fragment-order layout: tile is (rows x 32k) bf16, stored as 16-row
// subtiles of 512 elems; element (r,k) at sub(r>>4)*512 + (k>>3)*128 + (r&15)*8 + (k&7).
// A wave's MFMA fragment read = subtile base + lane*16B -> linear, conflict-free.
__device__ __forceinline__ int frag_off(int r, int kgrp8) {   // kgrp8 = k>>3
    return (r >> 4) * 512 + kgrp8 * 128 + (r & 15) * 8;
}

// ---------------- x fp32 -> bf16 pre-convert --------------------------------
__global__ __launch_bounds__(256) void cvtx_kernel(
    const float* __restrict__ x, __bf16* __restrict__ xb)
{
    const int i = (blockIdx.x * 256 + threadIdx.x) * 8;
    const f32x4 a = *(const f32x4*)(x + i);
    const f32x4 b = *(const f32x4*)(x + i + 4);
    *(bf16x8*)(xb + i) = cvt2_bf16(a, b);
}

// ---------------- Router: logits -> top-8 -> normalized weights -------------
__global__ __launch_bounds__(256) void router_kernel(
    const float* __restrict__ x, const float* __restrict__ gw,
    float* __restrict__ wdense, unsigned int* __restrict__ masks)
{
    const int t = blockIdx.x;
    const int tid = threadIdx.x;
    __shared__ float part[256];
    __shared__ float logits[E_NUM];
    const int e = tid & 31;
    const int chunk = tid >> 5;
    const float* xr = x + (size_t)t * H_DIM;
    const float* gr = gw + (size_t)e * H_DIM;
    const int base = chunk * (H_DIM / 8);
    float s = 0.f;
    for (int h = 0; h < H_DIM / 8; h += 4) {
        const f32x4 xv = *reinterpret_cast<const f32x4*>(xr + base + h);
        const f32x4 gv = *reinterpret_cast<const f32x4*>(gr + base + h);
        s += xv[0]*gv[0] + xv[1]*gv[1] + xv[2]*gv[2] + xv[3]*gv[3];
    }
    part[tid] = s;
    __syncthreads();
    if (tid < E_NUM) {
        float tot = 0.f;
        for (int c = 0; c < 8; ++c) tot += part[c * 32 + tid];
        logits[tid] = tot;
    }
    __syncthreads();
    if (tid == 0) {
        float l[E_NUM];
        for (int i = 0; i < E_NUM; ++i) {
            l[i] = logits[i];
            wdense[(size_t)t * E_NUM + i] = 0.f;
        }
        unsigned mask = 0;
        int   idx[K_TOP];
        float lv[K_TOP];
        for (int k = 0; k < K_TOP; ++k) {
            float best = -1e30f; int bi = 0;
            for (int i = 0; i < E_NUM; ++i)
                if (!((mask >> i) & 1u) && l[i] > best) { best = l[i]; bi = i; }
            mask |= (1u << bi); idx[k] = bi; lv[k] = best;
        }
        const float m = lv[0];
        float den = 0.f;
        for (int k = 0; k < K_TOP; ++k) den += expf(lv[k] - m);
        for (int k = 0; k < K_TOP; ++k)
            wdense[(size_t)t * E_NUM + idx[k]] = expf(lv[k] - m) / den;
        masks[t] = mask;
    }
}

// ---------------- Build compacted per-expert token lists --------------------
__global__ __launch_bounds__(256) void count_kernel(
    const unsigned int* __restrict__ masks, int* __restrict__ cnt)
{
    const int e = blockIdx.x;
    const int tid = threadIdx.x;
    int c = 0;
    for (int t = tid; t < T_TOK; t += 256) c += (masks[t] >> e) & 1u;
    __shared__ int red[256];
    red[tid] = c; __syncthreads();
    for (int s = 128; s > 0; s >>= 1) {
        if (tid < s) red[tid] += red[tid + s];
        __syncthreads();
    }
    if (tid == 0) cnt[e] = red[0];
}

__global__ void scan_kernel(const int* __restrict__ cnt, int* __restrict__ off)
{
    if (threadIdx.x == 0 && blockIdx.x == 0) {
        int r = 0;
        for (int e = 0; e < E_NUM; ++e) { off[e] = r; r += cnt[e]; }
    }
}

__global__ __launch_bounds__(256) void fill_kernel(
    const unsigned int* __restrict__ masks, const float* __restrict__ wdense,
    const int* __restrict__ off, int* __restrict__ tok, float* __restrict__ wgt)
{
    const int e = blockIdx.x;
    const int tid = threadIdx.x;
    const int PER = T_TOK / 256;
    int sel[PER]; int c = 0;
    for (int i = 0; i < PER; ++i) {
        const int t = tid * PER + i;
        sel[i] = (masks[t] >> e) & 1u;
        c += sel[i];
    }
    __shared__ int s[256];
    s[tid] = c; __syncthreads();
    if (tid == 0) {
        int r = 0;
        for (int j = 0; j < 256; ++j) { int v = s[j]; s[j] = r; r += v; }
    }
    __syncthreads();
    int pos = off[e] + s[tid];
    for (int i = 0; i < PER; ++i) {
        if (sel[i]) {
            const int t = tid * PER + i;
            tok[pos] = t;
            wgt[pos] = wdense[(size_t)t * E_NUM + e];
            pos++;
        }
    }
}

// ---------------- GEMM1: act = silu(x @ w1^T) * (x @ w3^T) ------------------
// grid (zt=8, I/64=12, E=32), block 256 (4 waves). Block: 128 tok x 128 Brows.
// Brows: [0:32)=gate lo, [32:64)=up lo, [64:96)=gate hi, [96:128)=up hi.
// Wave (2Mx2N): 64 tok x 64 Brows -> acc[4][4]; n=0,1 gate, n=2,3 up.
__global__ __launch_bounds__(256, 3) void gemm1_kernel(
    const __bf16* __restrict__ xb, const float* __restrict__ w13,
    const int* __restrict__ tok, const int* __restrict__ cnt,
    const int* __restrict__ off, unsigned short* __restrict__ act)
{
    const int e = blockIdx.z;
    const int c = cnt[e];
    const int m0 = blockIdx.x * 128;
    if (m0 >= c) return;
    const int o  = off[e];
    const int n0 = blockIdx.y * 64;
    const int tid  = threadIdx.x;
    const int wid  = tid >> 6;
    const int lane = tid & 63;
    const int wm = (wid >> 1) * 64;     // token offset: 0,64
    const int wn = (wid & 1);           // Brow half: 0,1 (x64)
    const int lrow = lane & 15;

    __shared__ __bf16 As[2][4096];      // 8 KB each buf
    __shared__ __bf16 Bs[2][4096];

    // staging: row sr = tid>>1 (0..127), k-half kh = tid&1 (16 elems)
    const int sr = tid >> 1;
    const int kh = tid & 1;
    int rA = m0 + sr; rA = rA < c ? rA : c - 1;
    const __bf16* xp = xb + (size_t)tok[o + rA] * H_DIM + kh * 16;
    const int grp = sr >> 5;
    const int wrow = (grp & 1) * I_DIM + n0 + (grp >> 1) * 32 + (sr & 31);
    const float* wp = w13 + (size_t)e * (2 * I_DIM) * H_DIM + (size_t)wrow * H_DIM + kh * 16;
    const int wo = frag_off(sr, kh * 2);    // first 8-group; second at +128

    bf16x8 ra[2];
    f32x4  rb[4];
    f32x4  acc[4][4] = {};

    ra[0] = *(const bf16x8*)(xp);
    ra[1] = *(const bf16x8*)(xp + 8);
#pragma unroll
    for (int i = 0; i < 4; ++i) rb[i] = *(const f32x4*)(wp + i * 4);
    *(bf16x8*)&As[0][wo]       = ra[0];
    *(bf16x8*)&As[0][wo + 128] = ra[1];
    *(bf16x8*)&Bs[0][wo]       = cvt2_bf16(rb[0], rb[1]);
    *(bf16x8*)&Bs[0][wo + 128] = cvt2_bf16(rb[2], rb[3]);
    __syncthreads();

    const int NS = H_DIM / BK;   // 64
    for (int s = 0; s < NS; ++s) {
        const int buf = s & 1;
        if (s + 1 < NS) {
            const int k = (s + 1) * BK;
            ra[0] = *(const bf16x8*)(xp + k);
            ra[1] = *(const bf16x8*)(xp + k + 8);
#pragma unroll
            for (int i = 0; i < 4; ++i) rb[i] = *(const f32x4*)(wp + k + i * 4);
        }
        bf16x8 af[4], bfr[4];
#pragma unroll
        for (int m = 0; m < 4; ++m)
            af[m] = *(const bf16x8*)&As[buf][((wm >> 4) + m) * 512 + lane * 8];
#pragma unroll
        for (int n = 0; n < 4; ++n)
            bfr[n] = *(const bf16x8*)&Bs[buf][(wn * 4 + n) * 512 + lane * 8];
#pragma unroll
        for (int m = 0; m < 4; ++m)
#pragma unroll
            for (int n = 0; n < 4; ++n)
                acc[m][n] = __builtin_amdgcn_mfma_f32_16x16x32_bf16(af[m], bfr[n], acc[m][n], 0, 0, 0);
        if (s + 1 < NS) {
            *(bf16x8*)&As[buf ^ 1][wo]       = ra[0];
            *(bf16x8*)&As[buf ^ 1][wo + 128] = ra[1];
            *(bf16x8*)&Bs[buf ^ 1][wo]       = cvt2_bf16(rb[0], rb[1]);
            *(bf16x8*)&Bs[buf ^ 1][wo + 128] = cvt2_bf16(rb[2], rb[3]);
        }
        __syncthreads();
    }

    // epilogue: n=0,1 gate, n=2,3 up; icol = n0 + wn*32 + n*16 + lrow
#pragma unroll
    for (int m = 0; m < 4; ++m)
#pragma unroll
        for (int n = 0; n < 2; ++n)
#pragma unroll
            for (int i = 0; i < 4; ++i) {
                const int row = m0 + wm + m * 16 + (lane >> 4) * 4 + i;
                if (row < c) {
                    const int icol = n0 + wn * 32 + n * 16 + lrow;
                    const float g = acc[m][n][i];
                    const float u = acc[m][n + 2][i];
                    const float a = (g / (1.f + expf(-g))) * u;
                    act[(size_t)(o + row) * I_DIM + icol] =
                        __builtin_bit_cast(unsigned short, (__bf16)a);
                }
            }
}

// ---------------- GEMM2: out[t] += wgt * (act @ w2^T) -----------------------
// grid (zt=8, H/128=16, E=32), block 256 (4 waves). Block: 128 tok x 128 H.
__global__ __launch_bounds__(256, 3) void gemm2_kernel(
    const unsigned short* __restrict__ act, const float* __restrict__ w2,
    const int* __restrict__ tok, const float* __restrict__ wgt,
    const int* __restrict__ cnt, const int* __restrict__ off,
    float* __restrict__ out)
{
    const int e = blockIdx.z;
    const int c = cnt[e];
    const int m0 = blockIdx.x * 128;
    if (m0 >= c) return;
    const int o  = off[e];
    const int n0 = blockIdx.y * 128;
    const int tid  = threadIdx.x;
    const int wid  = tid >> 6;
    const int lane = tid & 63;
    const int wm = (wid >> 1) * 64;
    const int wn = (wid & 1);
    const int lrow = lane & 15;

    __shared__ __bf16 As[2][4096];
    __shared__ __bf16 Bs[2][4096];

    const int sr = tid >> 1;
    const int kh = tid & 1;
    int rA = m0 + sr; rA = rA < c ? rA : c - 1;
    const unsigned short* ap = act + (size_t)(o + rA) * I_DIM + kh * 16;
    const float* wp = w2 + (size_t)e * H_DIM * I_DIM + (size_t)(n0 + sr) * I_DIM + kh * 16;
    const int wo = frag_off(sr, kh * 2);

    bf16x8 ra[2];
    f32x4  rb[4];
    f32x4  acc[4][4] = {};

    ra[0] = *(const bf16x8*)(ap);
    ra[1] = *(const bf16x8*)(ap + 8);
#pragma unroll
    for (int i = 0; i < 4; ++i) rb[i] = *(const f32x4*)(wp + i * 4);
    *(bf16x8*)&As[0][wo]       = ra[0];
    *(bf16x8*)&As[0][wo + 128] = ra[1];
    *(bf16x8*)&Bs[0][wo]       = cvt2_bf16(rb[0], rb[1]);
    *(bf16x8*)&Bs[0][wo + 128] = cvt2_bf16(rb[2], rb[3]);
    __syncthreads();

    const int NS = I_DIM / BK;   // 24
    for (int s = 0; s < NS; ++s) {
        const int buf = s & 1;
        if (s + 1 < NS) {
            const int k = (s + 1) * BK;
            ra[0] = *(const bf16x8*)(ap + k);
            ra[1] = *(const bf16x8*)(ap + k + 8);
#pragma unroll
            for (int i = 0; i < 4; ++i) rb[i] = *(const f32x4*)(wp + k + i * 4);
        }
        bf16x8 af[4], bfr[4];
#pragma unroll
        for (int m = 0; m < 4; ++m)
            af[m] = *(const bf16x8*)&As[buf][((wm >> 4) + m) * 512 + lane * 8];
#pragma unroll
        for (int n = 0; n < 4; ++n)
            bfr[n] = *(const bf16x8*)&Bs[buf][(wn * 4 + n) * 512 + lane * 8];
#pragma unroll
        for (int m = 0; m < 4; ++m)
#pragma unroll
            for (int n = 0; n < 4; ++n)
                acc[m][n] = __builtin_amdgcn_mfma_f32_16x16x32_bf16(af[m], bfr[n], acc[m][n], 0, 0, 0);
        if (s + 1 < NS) {
            *(bf16x8*)&As[buf ^ 1][wo]       = ra[0];
            *(bf16x8*)&As[buf ^ 1][wo + 128] = ra[1];
            *(bf16x8*)&Bs[buf ^ 1][wo]       = cvt2_bf16(rb[0], rb[1]);
            *(bf16x8*)&Bs[buf ^ 1][wo + 128] = cvt2_bf16(rb[2], rb[3]);
        }
        __syncthreads();
    }

#pragma unroll
    for (int m = 0; m < 4; ++m)
#pragma unroll
        for (int n = 0; n < 4; ++n)
#pragma unroll
            for (int i = 0; i < 4; ++i) {
                const int row = m0 + wm + m * 16 + (lane >> 4) * 4 + i;
                if (row < c) {
                    const int t = tok[o + row];
                    const float w = wgt[o + row];
                    const int hcol = n0 + wn * 64 + n * 16 + lrow;
                    atomicAdd(&out[(size_t)t * H_DIM + hcol], w * acc[m][n][i]);
                }
            }
}

// ---------------- Launch ----------------------------------------------------
extern "C" void kernel_launch(void* const* d_in, const int* in_sizes, int n_in,
                              void* d_out, int out_size, void* d_ws, size_t ws_size,
                              hipStream_t stream)
{
    const float* x   = (const float*)d_in[0];
    const float* gw  = (const float*)d_in[1];
    const float* w13 = (const float*)d_in[2];
    const float* w2  = (const float*)d_in[3];
    float* out = (float*)d_out;

    char* ws = (char*)d_ws;
    float*          wdense = (float*)(ws + 0x00000);
    unsigned int*   masks  = (unsigned int*)(ws + 0x20000);
    int*            cnt    = (int*)(ws + 0x21000);
    int*            off    = (int*)(ws + 0x22000);
    int*            tok    = (int*)(ws + 0x23000);
    float*          wgt    = (float*)(ws + 0x2B000);
    unsigned short* act    = (unsigned short*)(ws + 0x33000);   // 12.6 MB
    __bf16*         xb     = (__bf16*)(ws + 0xC40000);          // 4 MB

    hipMemsetAsync(d_out, 0, (size_t)out_size * sizeof(float), stream);

    cvtx_kernel<<<(T_TOK * H_DIM) / (256 * 8), 256, 0, stream>>>(x, xb);
    router_kernel<<<T_TOK, 256, 0, stream>>>(x, gw, wdense, masks);
    count_kernel<<<E_NUM, 256, 0, stream>>>(masks, cnt);
    scan_kernel<<<1, 64, 0, stream>>>(cnt, off);
    fill_kernel<<<E_NUM, 256, 0, stream>>>(masks, wdense, off, tok, wgt);
    gemm1_kernel<<<dim3(8, I_DIM / 64, E_NUM), 256, 0, stream>>>(
        xb, w13, tok, cnt, off, act);
    gemm2_kernel<<<dim3(8, H_DIM / 128, E_NUM), 256, 0, stream>>>(
        act, w2, tok, wgt, cnt, off, out);
}

// Round 5
// 440.077 us; speedup vs baseline: 2.3830x; 2.3797x over previous
//
#include <hip/hip_runtime.h>
#include <hip/hip_bf16.h>
#include <math.h>

#define T_TOK 1024
#define H_DIM 2048
#define I_DIM 768
#define E_NUM 32
#define K_TOP 8
#define BK 32
#define GRID_P 1024   // persistent grid: 4 blocks/CU x 256 CUs

typedef __bf16 bf16x8 __attribute__((ext_vector_type(8)));
typedef float  f32x4  __attribute__((ext_vector_type(4)));

__device__ __forceinline__ bf16x8 cvt2_bf16(const f32x4 a, const f32x4 b) {
    bf16x8 r;
    r[0] = (__bf16)a[0]; r[1] = (__bf16)a[1]; r[2] = (__bf16)a[2]; r[3] = (__bf16)a[3];
    r[4] = (__bf16)b[0]; r[5] = (__bf16)b[1]; r[6] = (__bf16)b[2]; r[7] = (__bf16)b[3];
    return r;
}

// LDS fragment-order layout: tile is (rows x 32k) bf16, stored as 16-row
// subtiles of 512 elems; element (r,k) at (r>>4)*512 + (k>>3)*128 + (r&15)*8 + (k&7).
// A wave's MFMA fragment read = subtile base + lane*16B -> linear.
__device__ __forceinline__ int frag_off(int r, int kgrp8) {
    return (r >> 4) * 512 + kgrp8 * 128 + (r & 15) * 8;
}

// ---------------- x fp32 -> bf16 pre-convert --------------------------------
__global__ __launch_bounds__(256) void cvtx_kernel(
    const float* __restrict__ x, __bf16* __restrict__ xb)
{
    const int i = (blockIdx.x * 256 + threadIdx.x) * 8;
    const f32x4 a = *(const f32x4*)(x + i);
    const f32x4 b = *(const f32x4*)(x + i + 4);
    *(bf16x8*)(xb + i) = cvt2_bf16(a, b);
}

// ---------------- Router: logits -> top-8 -> normalized weights -------------
__global__ __launch_bounds__(256) void router_kernel(
    const float* __restrict__ x, const float* __restrict__ gw,
    float* __restrict__ wdense, unsigned int* __restrict__ masks)
{
    const int t = blockIdx.x;
    const int tid = threadIdx.x;
    __shared__ float part[256];
    __shared__ float logits[E_NUM];
    const int e = tid & 31;
    const int chunk = tid >> 5;
    const float* xr = x + (size_t)t * H_DIM;
    const float* gr = gw + (size_t)e * H_DIM;
    const int base = chunk * (H_DIM / 8);
    float s = 0.f;
    for (int h = 0; h < H_DIM / 8; h += 4) {
        const f32x4 xv = *reinterpret_cast<const f32x4*>(xr + base + h);
        const f32x4 gv = *reinterpret_cast<const f32x4*>(gr + base + h);
        s += xv[0]*gv[0] + xv[1]*gv[1] + xv[2]*gv[2] + xv[3]*gv[3];
    }
    part[tid] = s;
    __syncthreads();
    if (tid < E_NUM) {
        float tot = 0.f;
        for (int c = 0; c < 8; ++c) tot += part[c * 32 + tid];
        logits[tid] = tot;
    }
    __syncthreads();
    if (tid == 0) {
        float l[E_NUM];
        for (int i = 0; i < E_NUM; ++i) {
            l[i] = logits[i];
            wdense[(size_t)t * E_NUM + i] = 0.f;
        }
        unsigned mask = 0;
        int   idx[K_TOP];
        float lv[K_TOP];
        for (int k = 0; k < K_TOP; ++k) {
            float best = -1e30f; int bi = 0;
            for (int i = 0; i < E_NUM; ++i)
                if (!((mask >> i) & 1u) && l[i] > best) { best = l[i]; bi = i; }
            mask |= (1u << bi); idx[k] = bi; lv[k] = best;
        }
        const float m = lv[0];
        float den = 0.f;
        for (int k = 0; k < K_TOP; ++k) den += expf(lv[k] - m);
        for (int k = 0; k < K_TOP; ++k)
            wdense[(size_t)t * E_NUM + idx[k]] = expf(lv[k] - m) / den;
        masks[t] = mask;
    }
}

// ---------------- Build compacted per-expert token lists --------------------
__global__ __launch_bounds__(256) void count_kernel(
    const unsigned int* __restrict__ masks, int* __restrict__ cnt)
{
    const int e = blockIdx.x;
    const int tid = threadIdx.x;
    int c = 0;
    for (int t = tid; t < T_TOK; t += 256) c += (masks[t] >> e) & 1u;
    __shared__ int red[256];
    red[tid] = c; __syncthreads();
    for (int s = 128; s > 0; s >>= 1) {
        if (tid < s) red[tid] += red[tid + s];
        __syncthreads();
    }
    if (tid == 0) cnt[e] = red[0];
}

// scan + live-tile table: tbl[0]=ntiles, tbl[1+i] = (e<<8)|zt  (128-token tiles)
__global__ void scan_kernel(const int* __restrict__ cnt, int* __restrict__ off,
                            int* __restrict__ tbl)
{
    if (threadIdx.x == 0 && blockIdx.x == 0) {
        int r = 0, nt = 0;
        for (int e = 0; e < E_NUM; ++e) {
            off[e] = r;
            const int c = cnt[e];
            r += c;
            const int t = (c + 127) >> 7;
            for (int z = 0; z < t; ++z) tbl[1 + nt++] = (e << 8) | z;
        }
        tbl[0] = nt;
    }
}

__global__ __launch_bounds__(256) void fill_kernel(
    const unsigned int* __restrict__ masks, const float* __restrict__ wdense,
    const int* __restrict__ off, int* __restrict__ tok, float* __restrict__ wgt)
{
    const int e = blockIdx.x;
    const int tid = threadIdx.x;
    const int PER = T_TOK / 256;
    int sel[PER]; int c = 0;
    for (int i = 0; i < PER; ++i) {
        const int t = tid * PER + i;
        sel[i] = (masks[t] >> e) & 1u;
        c += sel[i];
    }
    __shared__ int s[256];
    s[tid] = c; __syncthreads();
    if (tid == 0) {
        int r = 0;
        for (int j = 0; j < 256; ++j) { int v = s[j]; s[j] = r; r += v; }
    }
    __syncthreads();
    int pos = off[e] + s[tid];
    for (int i = 0; i < PER; ++i) {
        if (sel[i]) {
            const int t = tid * PER + i;
            tok[pos] = t;
            wgt[pos] = wdense[(size_t)t * E_NUM + e];
            pos++;
        }
    }
}

// ---------------- GEMM1: act = silu(x @ w1^T) * (x @ w3^T) ------------------
// Persistent: grid GRID_P, work w = tile*12 + nidx. Tile: 128 tok x 128 Brows
// (Brows: [0:32)=gate lo, [32:64)=up lo, [64:96)=gate hi, [96:128)=up hi).
// Wave (2Mx2N): 64 tok x 64 Brows -> acc[4][4]; n=0,1 gate, n=2,3 up.
__global__ __launch_bounds__(256, 3) void gemm1_kernel(
    const __bf16* __restrict__ xb, const float* __restrict__ w13,
    const int* __restrict__ tok, const int* __restrict__ cnt,
    const int* __restrict__ off, const int* __restrict__ tbl,
    unsigned short* __restrict__ act)
{
    __shared__ __bf16 As[2][4096];
    __shared__ __bf16 Bs[2][4096];
    const int tid  = threadIdx.x;
    const int wid  = tid >> 6;
    const int lane = tid & 63;
    const int wm = (wid >> 1) * 64;
    const int wn = (wid & 1);
    const int lrow = lane & 15;
    const int sr = tid >> 1;
    const int kh = tid & 1;
    const int wo = frag_off(sr, kh * 2);

    const int W = tbl[0] * 12;
    for (int w = blockIdx.x; w < W; w += gridDim.x) {
        const int ti   = w / 12;
        const int nidx = w - ti * 12;
        const int ez = tbl[1 + ti];
        const int e  = ez >> 8;
        const int m0 = (ez & 255) * 128;
        const int c  = cnt[e];
        const int o  = off[e];
        const int n0 = nidx * 64;

        int rA = m0 + sr; rA = rA < c ? rA : c - 1;
        const __bf16* xp = xb + (size_t)tok[o + rA] * H_DIM + kh * 16;
        const int grp = sr >> 5;
        const int wrow = (grp & 1) * I_DIM + n0 + (grp >> 1) * 32 + (sr & 31);
        const float* wp = w13 + (size_t)e * (2 * I_DIM) * H_DIM
                              + (size_t)wrow * H_DIM + kh * 16;

        bf16x8 ra[2];
        f32x4  rb[4];
        f32x4  acc[4][4] = {};

        ra[0] = *(const bf16x8*)(xp);
        ra[1] = *(const bf16x8*)(xp + 8);
#pragma unroll
        for (int i = 0; i < 4; ++i) rb[i] = *(const f32x4*)(wp + i * 4);
        *(bf16x8*)&As[0][wo]       = ra[0];
        *(bf16x8*)&As[0][wo + 128] = ra[1];
        *(bf16x8*)&Bs[0][wo]       = cvt2_bf16(rb[0], rb[1]);
        *(bf16x8*)&Bs[0][wo + 128] = cvt2_bf16(rb[2], rb[3]);
        __syncthreads();

        const int NS = H_DIM / BK;   // 64
        for (int s = 0; s < NS; ++s) {
            const int buf = s & 1;
            if (s + 1 < NS) {
                const int k = (s + 1) * BK;
                ra[0] = *(const bf16x8*)(xp + k);
                ra[1] = *(const bf16x8*)(xp + k + 8);
#pragma unroll
                for (int i = 0; i < 4; ++i) rb[i] = *(const f32x4*)(wp + k + i * 4);
            }
            bf16x8 af[4], bfr[4];
#pragma unroll
            for (int m = 0; m < 4; ++m)
                af[m] = *(const bf16x8*)&As[buf][((wm >> 4) + m) * 512 + lane * 8];
#pragma unroll
            for (int n = 0; n < 4; ++n)
                bfr[n] = *(const bf16x8*)&Bs[buf][(wn * 4 + n) * 512 + lane * 8];
#pragma unroll
            for (int m = 0; m < 4; ++m)
#pragma unroll
                for (int n = 0; n < 4; ++n)
                    acc[m][n] = __builtin_amdgcn_mfma_f32_16x16x32_bf16(af[m], bfr[n], acc[m][n], 0, 0, 0);
            if (s + 1 < NS) {
                *(bf16x8*)&As[buf ^ 1][wo]       = ra[0];
                *(bf16x8*)&As[buf ^ 1][wo + 128] = ra[1];
                *(bf16x8*)&Bs[buf ^ 1][wo]       = cvt2_bf16(rb[0], rb[1]);
                *(bf16x8*)&Bs[buf ^ 1][wo + 128] = cvt2_bf16(rb[2], rb[3]);
            }
            __syncthreads();
        }

        // epilogue: n=0,1 gate, n=2,3 up; icol = n0 + wn*32 + n*16 + lrow
#pragma unroll
        for (int m = 0; m < 4; ++m)
#pragma unroll
            for (int n = 0; n < 2; ++n)
#pragma unroll
                for (int i = 0; i < 4; ++i) {
                    const int row = m0 + wm + m * 16 + (lane >> 4) * 4 + i;
                    if (row < c) {
                        const int icol = n0 + wn * 32 + n * 16 + lrow;
                        const float g = acc[m][n][i];
                        const float u = acc[m][n + 2][i];
                        const float a = (g / (1.f + expf(-g))) * u;
                        act[(size_t)(o + row) * I_DIM + icol] =
                            __builtin_bit_cast(unsigned short, (__bf16)a);
                    }
                }
    }
}

// ---------------- GEMM2: out[t] += wgt * (act @ w2^T) -----------------------
// Persistent: work w = tile*16 + nidx. Tile: 128 tok x 128 H-cols.
__global__ __launch_bounds__(256, 3) void gemm2_kernel(
    const unsigned short* __restrict__ act, const float* __restrict__ w2,
    const int* __restrict__ tok, const float* __restrict__ wgt,
    const int* __restrict__ cnt, const int* __restrict__ off,
    const int* __restrict__ tbl, float* __restrict__ out)
{
    __shared__ __bf16 As[2][4096];
    __shared__ __bf16 Bs[2][4096];
    const int tid  = threadIdx.x;
    const int wid  = tid >> 6;
    const int lane = tid & 63;
    const int wm = (wid >> 1) * 64;
    const int wn = (wid & 1);
    const int lrow = lane & 15;
    const int sr = tid >> 1;
    const int kh = tid & 1;
    const int wo = frag_off(sr, kh * 2);

    const int W = tbl[0] * 16;
    for (int w = blockIdx.x; w < W; w += gridDim.x) {
        const int ti   = w >> 4;
        const int nidx = w & 15;
        const int ez = tbl[1 + ti];
        const int e  = ez >> 8;
        const int m0 = (ez & 255) * 128;
        const int c  = cnt[e];
        const int o  = off[e];
        const int n0 = nidx * 128;

        int rA = m0 + sr; rA = rA < c ? rA : c - 1;
        const unsigned short* ap = act + (size_t)(o + rA) * I_DIM + kh * 16;
        const float* wp = w2 + (size_t)e * H_DIM * I_DIM
                             + (size_t)(n0 + sr) * I_DIM + kh * 16;

        bf16x8 ra[2];
        f32x4  rb[4];
        f32x4  acc[4][4] = {};

        ra[0] = *(const bf16x8*)(ap);
        ra[1] = *(const bf16x8*)(ap + 8);
#pragma unroll
        for (int i = 0; i < 4; ++i) rb[i] = *(const f32x4*)(wp + i * 4);
        *(bf16x8*)&As[0][wo]       = ra[0];
        *(bf16x8*)&As[0][wo + 128] = ra[1];
        *(bf16x8*)&Bs[0][wo]       = cvt2_bf16(rb[0], rb[1]);
        *(bf16x8*)&Bs[0][wo + 128] = cvt2_bf16(rb[2], rb[3]);
        __syncthreads();

        const int NS = I_DIM / BK;   // 24
        for (int s = 0; s < NS; ++s) {
            const int buf = s & 1;
            if (s + 1 < NS) {
                const int k = (s + 1) * BK;
                ra[0] = *(const bf16x8*)(ap + k);
                ra[1] = *(const bf16x8*)(ap + k + 8);
#pragma unroll
                for (int i = 0; i < 4; ++i) rb[i] = *(const f32x4*)(wp + k + i * 4);
            }
            bf16x8 af[4], bfr[4];
#pragma unroll
            for (int m = 0; m < 4; ++m)
                af[m] = *(const bf16x8*)&As[buf][((wm >> 4) + m) * 512 + lane * 8];
#pragma unroll
            for (int n = 0; n < 4; ++n)
                bfr[n] = *(const bf16x8*)&Bs[buf][(wn * 4 + n) * 512 + lane * 8];
#pragma unroll
            for (int m = 0; m < 4; ++m)
#pragma unroll
                for (int n = 0; n < 4; ++n)
                    acc[m][n] = __builtin_amdgcn_mfma_f32_16x16x32_bf16(af[m], bfr[n], acc[m][n], 0, 0, 0);
            if (s + 1 < NS) {
                *(bf16x8*)&As[buf ^ 1][wo]       = ra[0];
                *(bf16x8*)&As[buf ^ 1][wo + 128] = ra[1];
                *(bf16x8*)&Bs[buf ^ 1][wo]       = cvt2_bf16(rb[0], rb[1]);
                *(bf16x8*)&Bs[buf ^ 1][wo + 128] = cvt2_bf16(rb[2], rb[3]);
            }
            __syncthreads();
        }

#pragma unroll
        for (int m = 0; m < 4; ++m)
#pragma unroll
            for (int n = 0; n < 4; ++n)
#pragma unroll
                for (int i = 0; i < 4; ++i) {
                    const int row = m0 + wm + m * 16 + (lane >> 4) * 4 + i;
                    if (row < c) {
                        const int t = tok[o + row];
                        const float wv = wgt[o + row];
                        const int hcol = n0 + wn * 64 + n * 16 + lrow;
                        atomicAdd(&out[(size_t)t * H_DIM + hcol], wv * acc[m][n][i]);
                    }
                }
    }
}

// ---------------- Launch ----------------------------------------------------
extern "C" void kernel_launch(void* const* d_in, const int* in_sizes, int n_in,
                              void* d_out, int out_size, void* d_ws, size_t ws_size,
                              hipStream_t stream)
{
    const float* x   = (const float*)d_in[0];
    const float* gw  = (const float*)d_in[1];
    const float* w13 = (const float*)d_in[2];
    const float* w2  = (const float*)d_in[3];
    float* out = (float*)d_out;

    char* ws = (char*)d_ws;
    float*          wdense = (float*)(ws + 0x00000);
    unsigned int*   masks  = (unsigned int*)(ws + 0x20000);
    int*            cnt    = (int*)(ws + 0x21000);
    int*            off    = (int*)(ws + 0x21800);
    int*            tbl    = (int*)(ws + 0x22000);
    int*            tok    = (int*)(ws + 0x23000);
    float*          wgt    = (float*)(ws + 0x2B000);
    unsigned short* act    = (unsigned short*)(ws + 0x33000);   // 12.6 MB
    __bf16*         xb     = (__bf16*)(ws + 0xC40000);          // 4 MB

    hipMemsetAsync(d_out, 0, (size_t)out_size * sizeof(float), stream);

    cvtx_kernel<<<(T_TOK * H_DIM) / (256 * 8), 256, 0, stream>>>(x, xb);
    router_kernel<<<T_TOK, 256, 0, stream>>>(x, gw, wdense, masks);
    count_kernel<<<E_NUM, 256, 0, stream>>>(masks, cnt);
    scan_kernel<<<1, 64, 0, stream>>>(cnt, off, tbl);
    fill_kernel<<<E_NUM, 256, 0, stream>>>(masks, wdense, off, tok, wgt);
    gemm1_kernel<<<GRID_P, 256, 0, stream>>>(xb, w13, tok, cnt, off, tbl, act);
    gemm2_kernel<<<GRID_P, 256, 0, stream>>>(act, w2, tok, wgt, cnt, off, tbl, out);
}

// Round 6
// 384.291 us; speedup vs baseline: 2.7289x; 1.1452x over previous
//
#include <hip/hip_runtime.h>
#include <hip/hip_bf16.h>
#include <math.h>

#define T_TOK 1024
#define H_DIM 2048
#define I_DIM 768
#define E_NUM 32
#define K_TOP 8
#define BK 32
#define GRID_P 1024   // persistent grid: 256 CUs x up to 4 blocks

typedef __bf16 bf16x8 __attribute__((ext_vector_type(8)));
typedef float  f32x4  __attribute__((ext_vector_type(4)));

__device__ __forceinline__ bf16x8 cvt2_bf16(const f32x4 a, const f32x4 b) {
    bf16x8 r;
    r[0] = (__bf16)a[0]; r[1] = (__bf16)a[1]; r[2] = (__bf16)a[2]; r[3] = (__bf16)a[3];
    r[4] = (__bf16)b[0]; r[5] = (__bf16)b[1]; r[6] = (__bf16)b[2]; r[7] = (__bf16)b[3];
    return r;
}

// LDS fragment-order layout: tile is (rows x 32k) bf16, stored as 16-row
// subtiles of 512 elems; element (r,k) at (r>>4)*512 + (k>>3)*128 + (r&15)*8 + (k&7).
// A wave's MFMA fragment read = subtile base + lane*16B -> linear, conflict-free.
__device__ __forceinline__ int frag_off(int r, int kgrp8) {
    return (r >> 4) * 512 + kgrp8 * 128 + (r & 15) * 8;
}

// ---------------- x fp32 -> bf16 pre-convert --------------------------------
__global__ __launch_bounds__(256) void cvtx_kernel(
    const float* __restrict__ x, __bf16* __restrict__ xb)
{
    const int i = (blockIdx.x * 256 + threadIdx.x) * 8;
    const f32x4 a = *(const f32x4*)(x + i);
    const f32x4 b = *(const f32x4*)(x + i + 4);
    *(bf16x8*)(xb + i) = cvt2_bf16(a, b);
}

// ---------------- Router: logits -> top-8 -> normalized weights -------------
__global__ __launch_bounds__(256) void router_kernel(
    const float* __restrict__ x, const float* __restrict__ gw,
    float* __restrict__ wdense, unsigned int* __restrict__ masks)
{
    const int t = blockIdx.x;
    const int tid = threadIdx.x;
    __shared__ float part[256];
    __shared__ float logits[E_NUM];
    const int e = tid & 31;
    const int chunk = tid >> 5;
    const float* xr = x + (size_t)t * H_DIM;
    const float* gr = gw + (size_t)e * H_DIM;
    const int base = chunk * (H_DIM / 8);
    float s = 0.f;
    for (int h = 0; h < H_DIM / 8; h += 4) {
        const f32x4 xv = *reinterpret_cast<const f32x4*>(xr + base + h);
        const f32x4 gv = *reinterpret_cast<const f32x4*>(gr + base + h);
        s += xv[0]*gv[0] + xv[1]*gv[1] + xv[2]*gv[2] + xv[3]*gv[3];
    }
    part[tid] = s;
    __syncthreads();
    if (tid < E_NUM) {
        float tot = 0.f;
        for (int c = 0; c < 8; ++c) tot += part[c * 32 + tid];
        logits[tid] = tot;
    }
    __syncthreads();
    if (tid == 0) {
        float l[E_NUM];
        for (int i = 0; i < E_NUM; ++i) {
            l[i] = logits[i];
            wdense[(size_t)t * E_NUM + i] = 0.f;
        }
        unsigned mask = 0;
        int   idx[K_TOP];
        float lv[K_TOP];
        for (int k = 0; k < K_TOP; ++k) {
            float best = -1e30f; int bi = 0;
            for (int i = 0; i < E_NUM; ++i)
                if (!((mask >> i) & 1u) && l[i] > best) { best = l[i]; bi = i; }
            mask |= (1u << bi); idx[k] = bi; lv[k] = best;
        }
        const float m = lv[0];
        float den = 0.f;
        for (int k = 0; k < K_TOP; ++k) den += expf(lv[k] - m);
        for (int k = 0; k < K_TOP; ++k)
            wdense[(size_t)t * E_NUM + idx[k]] = expf(lv[k] - m) / den;
        masks[t] = mask;
    }
}

// ---------------- Build compacted per-expert token lists --------------------
__global__ __launch_bounds__(256) void count_kernel(
    const unsigned int* __restrict__ masks, int* __restrict__ cnt)
{
    const int e = blockIdx.x;
    const int tid = threadIdx.x;
    int c = 0;
    for (int t = tid; t < T_TOK; t += 256) c += (masks[t] >> e) & 1u;
    __shared__ int red[256];
    red[tid] = c; __syncthreads();
    for (int s = 128; s > 0; s >>= 1) {
        if (tid < s) red[tid] += red[tid + s];
        __syncthreads();
    }
    if (tid == 0) cnt[e] = red[0];
}

// scan + live-tile table: tbl[0]=ntiles, tbl[1+i] = (e<<8)|zt  (128-token tiles)
__global__ void scan_kernel(const int* __restrict__ cnt, int* __restrict__ off,
                            int* __restrict__ tbl)
{
    if (threadIdx.x == 0 && blockIdx.x == 0) {
        int r = 0, nt = 0;
        for (int e = 0; e < E_NUM; ++e) {
            off[e] = r;
            const int c = cnt[e];
            r += c;
            const int t = (c + 127) >> 7;
            for (int z = 0; z < t; ++z) tbl[1 + nt++] = (e << 8) | z;
        }
        tbl[0] = nt;
    }
}

__global__ __launch_bounds__(256) void fill_kernel(
    const unsigned int* __restrict__ masks, const float* __restrict__ wdense,
    const int* __restrict__ off, int* __restrict__ tok, float* __restrict__ wgt)
{
    const int e = blockIdx.x;
    const int tid = threadIdx.x;
    const int PER = T_TOK / 256;
    int sel[PER]; int c = 0;
    for (int i = 0; i < PER; ++i) {
        const int t = tid * PER + i;
        sel[i] = (masks[t] >> e) & 1u;
        c += sel[i];
    }
    __shared__ int s[256];
    s[tid] = c; __syncthreads();
    if (tid == 0) {
        int r = 0;
        for (int j = 0; j < 256; ++j) { int v = s[j]; s[j] = r; r += v; }
    }
    __syncthreads();
    int pos = off[e] + s[tid];
    for (int i = 0; i < PER; ++i) {
        if (sel[i]) {
            const int t = tid * PER + i;
            tok[pos] = t;
            wgt[pos] = wdense[(size_t)t * E_NUM + e];
            pos++;
        }
    }
}

// Phase macro for gemm1: read buf P, prefetch L(scur+2) into regset P,
// write regset Q (=L(scur+1)) into buf Q. Raw barrier, NO vmcnt drain.
#define G1_PHASE(P, Q)                                                         \
  {                                                                            \
    if (scur + 2 < NS) {                                                       \
      const int kk = (scur + 2) * BK;                                          \
      pa##P##_0 = *(const bf16x8*)(xp + kk);                                   \
      pa##P##_1 = *(const bf16x8*)(xp + kk + 8);                               \
      pb##P##_0 = *(const f32x4*)(wp + kk);                                    \
      pb##P##_1 = *(const f32x4*)(wp + kk + 4);                                \
      pb##P##_2 = *(const f32x4*)(wp + kk + 8);                                \
      pb##P##_3 = *(const f32x4*)(wp + kk + 12);                               \
    }                                                                          \
    bf16x8 af[4], bfr[4];                                                      \
    _Pragma("unroll")                                                          \
    for (int m = 0; m < 4; ++m)                                                \
      af[m] = *(const bf16x8*)&As[P][((wm >> 4) + m) * 512 + lane * 8];        \
    _Pragma("unroll")                                                          \
    for (int n = 0; n < 4; ++n)                                                \
      bfr[n] = *(const bf16x8*)&Bs[P][(wn * 4 + n) * 512 + lane * 8];          \
    _Pragma("unroll")                                                          \
    for (int m = 0; m < 4; ++m)                                                \
      _Pragma("unroll")                                                        \
      for (int n = 0; n < 4; ++n)                                              \
        acc[m][n] = __builtin_amdgcn_mfma_f32_16x16x32_bf16(af[m], bfr[n],     \
                                                            acc[m][n], 0,0,0); \
    if (scur + 1 < NS) {                                                       \
      *(bf16x8*)&As[Q][wo]       = pa##Q##_0;                                  \
      *(bf16x8*)&As[Q][wo + 128] = pa##Q##_1;                                  \
      *(bf16x8*)&Bs[Q][wo]       = cvt2_bf16(pb##Q##_0, pb##Q##_1);            \
      *(bf16x8*)&Bs[Q][wo + 128] = cvt2_bf16(pb##Q##_2, pb##Q##_3);            \
    }                                                                          \
    asm volatile("s_waitcnt lgkmcnt(0)" ::: "memory");                         \
    __builtin_amdgcn_s_barrier();                                              \
    ++scur;                                                                    \
  }

// ---------------- GEMM1: act = silu(x @ w1^T) * (x @ w3^T) ------------------
// Persistent: work w = tile*12 + nidx. Tile: 128 tok x 128 Brows
// (Brows: [0:32)=gate lo, [32:64)=up lo, [64:96)=gate hi, [96:128)=up hi).
// Wave (2Mx2N): 64 tok x 64 Brows -> acc[4][4]; n=0,1 gate, n=2,3 up.
__global__ __launch_bounds__(256, 3) void gemm1_kernel(
    const __bf16* __restrict__ xb, const float* __restrict__ w13,
    const int* __restrict__ tok, const int* __restrict__ cnt,
    const int* __restrict__ off, const int* __restrict__ tbl,
    unsigned short* __restrict__ act)
{
    __shared__ __bf16 As[2][4096];
    __shared__ __bf16 Bs[2][4096];
    const int tid  = threadIdx.x;
    const int wid  = tid >> 6;
    const int lane = tid & 63;
    const int wm = (wid >> 1) * 64;
    const int wn = (wid & 1);
    const int lrow = lane & 15;
    const int sr = tid >> 1;
    const int kh = tid & 1;
    const int wo = frag_off(sr, kh * 2);
    const int NS = H_DIM / BK;   // 64

    const int W = tbl[0] * 12;
    for (int w = blockIdx.x; w < W; w += gridDim.x) {
        const int ti   = w / 12;
        const int nidx = w - ti * 12;
        const int ez = tbl[1 + ti];
        const int e  = ez >> 8;
        const int m0 = (ez & 255) * 128;
        const int c  = cnt[e];
        const int o  = off[e];
        const int n0 = nidx * 64;

        int rA = m0 + sr; rA = rA < c ? rA : c - 1;
        const __bf16* xp = xb + (size_t)tok[o + rA] * H_DIM + kh * 16;
        const int grp = sr >> 5;
        const int wrow = (grp & 1) * I_DIM + n0 + (grp >> 1) * 32 + (sr & 31);
        const float* wp = w13 + (size_t)e * (2 * I_DIM) * H_DIM
                              + (size_t)wrow * H_DIM + kh * 16;

        bf16x8 pa0_0, pa0_1, pa1_0, pa1_1;
        f32x4  pb0_0, pb0_1, pb0_2, pb0_3, pb1_0, pb1_1, pb1_2, pb1_3;
        f32x4  acc[4][4] = {};

        // prologue: issue L0 (set0) and L1 (set1); write L0 -> buf0
        pa0_0 = *(const bf16x8*)(xp);
        pa0_1 = *(const bf16x8*)(xp + 8);
        pb0_0 = *(const f32x4*)(wp);
        pb0_1 = *(const f32x4*)(wp + 4);
        pb0_2 = *(const f32x4*)(wp + 8);
        pb0_3 = *(const f32x4*)(wp + 12);
        pa1_0 = *(const bf16x8*)(xp + BK);
        pa1_1 = *(const bf16x8*)(xp + BK + 8);
        pb1_0 = *(const f32x4*)(wp + BK);
        pb1_1 = *(const f32x4*)(wp + BK + 4);
        pb1_2 = *(const f32x4*)(wp + BK + 8);
        pb1_3 = *(const f32x4*)(wp + BK + 12);
        *(bf16x8*)&As[0][wo]       = pa0_0;
        *(bf16x8*)&As[0][wo + 128] = pa0_1;
        *(bf16x8*)&Bs[0][wo]       = cvt2_bf16(pb0_0, pb0_1);
        *(bf16x8*)&Bs[0][wo + 128] = cvt2_bf16(pb0_2, pb0_3);
        asm volatile("s_waitcnt lgkmcnt(0)" ::: "memory");
        __builtin_amdgcn_s_barrier();

        int scur = 0;
        for (int it = 0; it < NS; it += 2) {
            G1_PHASE(0, 1)
            G1_PHASE(1, 0)
        }

        // epilogue: n=0,1 gate, n=2,3 up; icol = n0 + wn*32 + n*16 + lrow
#pragma unroll
        for (int m = 0; m < 4; ++m)
#pragma unroll
            for (int n = 0; n < 2; ++n)
#pragma unroll
                for (int i = 0; i < 4; ++i) {
                    const int row = m0 + wm + m * 16 + (lane >> 4) * 4 + i;
                    if (row < c) {
                        const int icol = n0 + wn * 32 + n * 16 + lrow;
                        const float g = acc[m][n][i];
                        const float u = acc[m][n + 2][i];
                        const float a = (g / (1.f + expf(-g))) * u;
                        act[(size_t)(o + row) * I_DIM + icol] =
                            __builtin_bit_cast(unsigned short, (__bf16)a);
                    }
                }
    }
}

// Phase macro for gemm2 (A already bf16).
#define G2_PHASE(P, Q)                                                         \
  {                                                                            \
    if (scur + 2 < NS) {                                                       \
      const int kk = (scur + 2) * BK;                                          \
      qa##P##_0 = *(const bf16x8*)(ap + kk);                                   \
      qa##P##_1 = *(const bf16x8*)(ap + kk + 8);                               \
      qb##P##_0 = *(const f32x4*)(wp + kk);                                    \
      qb##P##_1 = *(const f32x4*)(wp + kk + 4);                                \
      qb##P##_2 = *(const f32x4*)(wp + kk + 8);                                \
      qb##P##_3 = *(const f32x4*)(wp + kk + 12);                               \
    }                                                                          \
    bf16x8 af[4], bfr[4];                                                      \
    _Pragma("unroll")                                                          \
    for (int m = 0; m < 4; ++m)                                                \
      af[m] = *(const bf16x8*)&As[P][((wm >> 4) + m) * 512 + lane * 8];        \
    _Pragma("unroll")                                                          \
    for (int n = 0; n < 4; ++n)                                                \
      bfr[n] = *(const bf16x8*)&Bs[P][(wn * 4 + n) * 512 + lane * 8];          \
    _Pragma("unroll")                                                          \
    for (int m = 0; m < 4; ++m)                                                \
      _Pragma("unroll")                                                        \
      for (int n = 0; n < 4; ++n)                                              \
        acc[m][n] = __builtin_amdgcn_mfma_f32_16x16x32_bf16(af[m], bfr[n],     \
                                                            acc[m][n], 0,0,0); \
    if (scur + 1 < NS) {                                                       \
      *(bf16x8*)&As[Q][wo]       = qa##Q##_0;                                  \
      *(bf16x8*)&As[Q][wo + 128] = qa##Q##_1;                                  \
      *(bf16x8*)&Bs[Q][wo]       = cvt2_bf16(qb##Q##_0, qb##Q##_1);            \
      *(bf16x8*)&Bs[Q][wo + 128] = cvt2_bf16(qb##Q##_2, qb##Q##_3);            \
    }                                                                          \
    asm volatile("s_waitcnt lgkmcnt(0)" ::: "memory");                         \
    __builtin_amdgcn_s_barrier();                                              \
    ++scur;                                                                    \
  }

// ---------------- GEMM2: out[t] += wgt * (act @ w2^T) -----------------------
// Persistent: work w = tile*16 + nidx. Tile: 128 tok x 128 H-cols.
__global__ __launch_bounds__(256, 3) void gemm2_kernel(
    const unsigned short* __restrict__ act, const float* __restrict__ w2,
    const int* __restrict__ tok, const float* __restrict__ wgt,
    const int* __restrict__ cnt, const int* __restrict__ off,
    const int* __restrict__ tbl, float* __restrict__ out)
{
    __shared__ __bf16 As[2][4096];
    __shared__ __bf16 Bs[2][4096];
    const int tid  = threadIdx.x;
    const int wid  = tid >> 6;
    const int lane = tid & 63;
    const int wm = (wid >> 1) * 64;
    const int wn = (wid & 1);
    const int lrow = lane & 15;
    const int sr = tid >> 1;
    const int kh = tid & 1;
    const int wo = frag_off(sr, kh * 2);
    const int NS = I_DIM / BK;   // 24

    const int W = tbl[0] * 16;
    for (int w = blockIdx.x; w < W; w += gridDim.x) {
        const int ti   = w >> 4;
        const int nidx = w & 15;
        const int ez = tbl[1 + ti];
        const int e  = ez >> 8;
        const int m0 = (ez & 255) * 128;
        const int c  = cnt[e];
        const int o  = off[e];
        const int n0 = nidx * 128;

        int rA = m0 + sr; rA = rA < c ? rA : c - 1;
        const __bf16* ap = (const __bf16*)act + (size_t)(o + rA) * I_DIM + kh * 16;
        const float* wp = w2 + (size_t)e * H_DIM * I_DIM
                             + (size_t)(n0 + sr) * I_DIM + kh * 16;

        bf16x8 qa0_0, qa0_1, qa1_0, qa1_1;
        f32x4  qb0_0, qb0_1, qb0_2, qb0_3, qb1_0, qb1_1, qb1_2, qb1_3;
        f32x4  acc[4][4] = {};

        qa0_0 = *(const bf16x8*)(ap);
        qa0_1 = *(const bf16x8*)(ap + 8);
        qb0_0 = *(const f32x4*)(wp);
        qb0_1 = *(const f32x4*)(wp + 4);
        qb0_2 = *(const f32x4*)(wp + 8);
        qb0_3 = *(const f32x4*)(wp + 12);
        qa1_0 = *(const bf16x8*)(ap + BK);
        qa1_1 = *(const bf16x8*)(ap + BK + 8);
        qb1_0 = *(const f32x4*)(wp + BK);
        qb1_1 = *(const f32x4*)(wp + BK + 4);
        qb1_2 = *(const f32x4*)(wp + BK + 8);
        qb1_3 = *(const f32x4*)(wp + BK + 12);
        *(bf16x8*)&As[0][wo]       = qa0_0;
        *(bf16x8*)&As[0][wo + 128] = qa0_1;
        *(bf16x8*)&Bs[0][wo]       = cvt2_bf16(qb0_0, qb0_1);
        *(bf16x8*)&Bs[0][wo + 128] = cvt2_bf16(qb0_2, qb0_3);
        asm volatile("s_waitcnt lgkmcnt(0)" ::: "memory");
        __builtin_amdgcn_s_barrier();

        int scur = 0;
        for (int it = 0; it < NS; it += 2) {
            G2_PHASE(0, 1)
            G2_PHASE(1, 0)
        }

#pragma unroll
        for (int m = 0; m < 4; ++m)
#pragma unroll
            for (int n = 0; n < 4; ++n)
#pragma unroll
                for (int i = 0; i < 4; ++i) {
                    const int row = m0 + wm + m * 16 + (lane >> 4) * 4 + i;
                    if (row < c) {
                        const int t = tok[o + row];
                        const float wv = wgt[o + row];
                        const int hcol = n0 + wn * 64 + n * 16 + lrow;
                        atomicAdd(&out[(size_t)t * H_DIM + hcol], wv * acc[m][n][i]);
                    }
                }
    }
}

// ---------------- Launch ----------------------------------------------------
extern "C" void kernel_launch(void* const* d_in, const int* in_sizes, int n_in,
                              void* d_out, int out_size, void* d_ws, size_t ws_size,
                              hipStream_t stream)
{
    const float* x   = (const float*)d_in[0];
    const float* gw  = (const float*)d_in[1];
    const float* w13 = (const float*)d_in[2];
    const float* w2  = (const float*)d_in[3];
    float* out = (float*)d_out;

    char* ws = (char*)d_ws;
    float*          wdense = (float*)(ws + 0x00000);
    unsigned int*   masks  = (unsigned int*)(ws + 0x20000);
    int*            cnt    = (int*)(ws + 0x21000);
    int*            off    = (int*)(ws + 0x21800);
    int*            tbl    = (int*)(ws + 0x22000);
    int*            tok    = (int*)(ws + 0x23000);
    float*          wgt    = (float*)(ws + 0x2B000);
    unsigned short* act    = (unsigned short*)(ws + 0x33000);   // 12.6 MB
    __bf16*         xb     = (__bf16*)(ws + 0xC40000);          // 4 MB

    hipMemsetAsync(d_out, 0, (size_t)out_size * sizeof(float), stream);

    cvtx_kernel<<<(T_TOK * H_DIM) / (256 * 8), 256, 0, stream>>>(x, xb);
    router_kernel<<<T_TOK, 256, 0, stream>>>(x, gw, wdense, masks);
    count_kernel<<<E_NUM, 256, 0, stream>>>(masks, cnt);
    scan_kernel<<<1, 64, 0, stream>>>(cnt, off, tbl);
    fill_kernel<<<E_NUM, 256, 0, stream>>>(masks, wdense, off, tok, wgt);
    gemm1_kernel<<<GRID_P, 256, 0, stream>>>(xb, w13, tok, cnt, off, tbl, act);
    gemm2_kernel<<<GRID_P, 256, 0, stream>>>(act, w2, tok, wgt, cnt, off, tbl, out);
}